// Round 18
// baseline (460.906 us; speedup 1.0000x reference)
//
#include <hip/hip_runtime.h>
#include <hip/hip_bf16.h>

#define NN 50000
#define NE 800000
#define NG 50
#define NSL 16    // pool slices per graph
#define NSCB 196  // scan blocks (196*256 = 50176 >= NN+1 nodes)
#define NNP (NSCB * 256)        // padded node count 50176
#define NC8 (NNP * 8)           // cnt8/excl8 size 401408

typedef unsigned short u16;
typedef unsigned int u32;
typedef __attribute__((ext_vector_type(8))) short short8;
typedef __attribute__((ext_vector_type(4))) float float4v;
typedef __attribute__((ext_vector_type(2))) float f32x2;

__device__ __forceinline__ float b2f(u16 u) {
    union { u32 i; float f; } v; v.i = ((u32)u) << 16; return v.f;
}
__device__ __forceinline__ u16 f2b(float f) {
    union { float f; u32 i; } v; v.f = f;
    u32 i = v.i;
    return (u16)((i + 0x7FFFu + ((i >> 16) & 1u)) >> 16);
}
__device__ __forceinline__ float lo16f(u32 u) { union { u32 i; float f; } v; v.i = u << 16; return v.f; }
__device__ __forceinline__ float hi16f(u32 u) { union { u32 i; float f; } v; v.i = u & 0xffff0000u; return v.f; }

// ---------------- init + detect + gaussian-coef precompute ----------------
struct SgP { const float* mu[4]; const float* sg[4]; };
__global__ void k_init(const int* __restrict__ ei_raw, int* flag,
                       int* cnt8, int* startg, int* endg, SgP S, float* __restrict__ gcoef) {
    __shared__ int cs[256];
    int i = blockIdx.x * blockDim.x + threadIdx.x;
    if (i < NC8) cnt8[i] = 0;
    if (i < NG) { startg[i] = 0x7fffffff; endg[i] = 0; }
    if (blockIdx.x == 0 && threadIdx.x < 64) {
        int t = threadIdx.x;          // [l][k][d] coef then [l][k][d] mu
        int l = (t >> 3) & 3, kd = t & 7;
        if (t < 32) {
            float s = S.sg[l][kd];
            gcoef[t] = -0.5f / (1e-15f + s * s);
        } else {
            gcoef[t] = S.mu[l][kd];   // gcoef[32 + l*8 + kd]
        }
    }
    if (blockIdx.x == 1) {
        int t = threadIdx.x;
        cs[t] = (ei_raw[2 * t + 1] == 0) ? 1 : 0;
        __syncthreads();
        for (int d = 128; d > 0; d >>= 1) {
            if (t < d) cs[t] += cs[t + d];
            __syncthreads();
        }
        if (t == 0) *flag = (cs[0] >= 128) ? 1 : 0;
    }
}

// ---------------- cvt + prep mega-fusion: XCD-sharded rank-hist | x2b | wprep | bounds ----------------
struct WParams { const float* g[4]; const float* rw[4]; };
__global__ void k_cvtprep(const int* __restrict__ ei_raw, const int* __restrict__ batch_raw,
                          const int* __restrict__ flag, int* cnt8, u16* __restrict__ rank,
                          const float* __restrict__ x, u16* __restrict__ xb,
                          WParams P, u16* __restrict__ bsw,
                          int* startg, int* endg) {
    int b = blockIdx.x, t = threadIdx.x;
    if (b < 3125) {                        // rank histogram: NE = 3125*256, color = b&7 (XCD shard)
        int e = b * 256 + t;
        int w = *flag;
        int color = b & 7;
        int d = w ? ei_raw[2 * (NE + e)] : ei_raw[NE + e];
        rank[e] = (u16)atomicAdd(&cnt8[d * 8 + color], 1);
    } else if (b < 15625) {                // x2b: NN*64 = 3.2M
        int i = (b - 3125) * 256 + t;
        if (i < NN * 64) xb[i] = f2b(x[i]);
    } else if (b < 15945) {                // wprep: 4*20480 ids
        int id = (b - 15625) * 256 + t;
        if (id < 4 * 20480) {
            int l = id / 20480, r = id % 20480;
            int j = r & 7, lane = (r >> 3) & 63, ctkt = r >> 9;
            int ct = ctkt & 3, kt = ctkt >> 2;
            int k = kt * 32 + (lane >> 4) * 8 + j;
            int n = ct * 16 + (lane & 15);
            float v;
            if (k < 256) v = P.g[l][(k & 63) * 256 + (k >> 6) * 64 + n];
            else         v = P.rw[l][(k - 256) * 64 + n];
            bsw[id] = f2b(v);
        }
    } else {                               // bounds: boundary scan on raw batch
        int n = (b - 15945) * 256 + t;
        if (n >= NN) return;
        int w = *flag;
        int bb = w ? batch_raw[2 * n] : batch_raw[n];
        if (n == 0) {
            startg[bb] = 0;
        } else {
            int bp = w ? batch_raw[2 * (n - 1)] : batch_raw[n - 1];
            if (bp != bb) { startg[bb] = n; endg[bp] = n; }
        }
        if (n == NN - 1) endg[bb] = NN;
    }
}

// ---------------- scan A: one thread per node scans its 8 colors; block-scan of node sums ----------------
__global__ __launch_bounds__(256) void k_scanA(const int* __restrict__ cnt8, int* __restrict__ excl8,
                                               int* __restrict__ bsum) {
    __shared__ int s[256];
    int t = threadIdx.x, b = blockIdx.x;
    int n = b * 256 + t;                  // node (padded)
    uint4 c0 = *(const uint4*)(cnt8 + (size_t)n * 8);
    uint4 c1 = *(const uint4*)(cnt8 + (size_t)n * 8 + 4);
    int v = c0.x + c0.y + c0.z + c0.w + c1.x + c1.y + c1.z + c1.w;
    s[t] = v; __syncthreads();
    for (int d = 1; d < 256; d <<= 1) {
        int x = s[t];
        int y = (t >= d) ? s[t - d] : 0;
        __syncthreads();
        s[t] = x + y;
        __syncthreads();
    }
    int run = s[t] - v;                   // exclusive prefix within block
    uint4 e0, e1;
    e0.x = run;            e0.y = run + c0.x;
    e0.z = e0.y + c0.y;    e0.w = e0.z + c0.z;
    e1.x = e0.w + c0.w;    e1.y = e1.x + c1.x;
    e1.z = e1.y + c1.y;    e1.w = e1.z + c1.z;
    *(uint4*)(excl8 + (size_t)n * 8) = e0;
    *(uint4*)(excl8 + (size_t)n * 8 + 4) = e1;
    if (t == 255) bsum[b] = s[255];
}

// ---------------- scan B+C fused: every block re-scans bsum locally, writes off8 ----------------
__global__ __launch_bounds__(256) void k_scanBC(const int* __restrict__ excl8,
                                                const int* __restrict__ bsum,
                                                int* __restrict__ off8) {
    __shared__ int s[256];
    int t = threadIdx.x, b = blockIdx.x;
    int v = (t < NSCB) ? bsum[t] : 0;
    s[t] = v; __syncthreads();
    for (int d = 1; d < 256; d <<= 1) {
        int x = s[t];
        int y = (t >= d) ? s[t - d] : 0;
        __syncthreads();
        s[t] = x + y;
        __syncthreads();
    }
    int ebase = (b == 0) ? 0 : s[b - 1];
    int n = b * 256 + t;
    uint4 e0 = *(const uint4*)(excl8 + (size_t)n * 8);
    uint4 e1 = *(const uint4*)(excl8 + (size_t)n * 8 + 4);
    e0.x += ebase; e0.y += ebase; e0.z += ebase; e0.w += ebase;
    e1.x += ebase; e1.y += ebase; e1.z += ebase; e1.w += ebase;
    *(uint4*)(off8 + (size_t)n * 8) = e0;
    *(uint4*)(off8 + (size_t)n * 8 + 4) = e1;
}

// ---------------- scatter: atomic-free, slot = off8[dst*8+color] + rank ----------------
__global__ void k_scatter(const int* __restrict__ ei_raw, const int* __restrict__ flag,
                          const int* __restrict__ off8, const u16* __restrict__ rank,
                          int* __restrict__ eid) {
    int e = blockIdx.x * blockDim.x + threadIdx.x;
    if (e >= NE) return;
    int w = *flag;
    int color = (e >> 8) & 7;             // matches k_cvtprep's block color
    int d = w ? ei_raw[2 * (NE + e)] : ei_raw[NE + e];
    eid[off8[d * 8 + color] + (int)rank[e]] = e;
}

// ---------------- gw pack: precomputed coefs, __expf; write asrc + agw ----------------
__global__ __launch_bounds__(256) void k_gwpack(const int* __restrict__ eid,
                                                const int* __restrict__ ei_raw,
                                                const float2* __restrict__ eattr2,
                                                const int* __restrict__ flag,
                                                const float* __restrict__ gcoef,
                                                u32* __restrict__ asrc, uint2* __restrict__ agw) {
    int j = blockIdx.x * blockDim.x + threadIdx.x;
    if (j >= NE) return;
    int e = eid[j];
    int w = *flag;
    int s = w ? ei_raw[2 * e] : ei_raw[e];
    float2 at = eattr2[e];
    float a0 = at.x, a1 = at.y;
    asrc[j] = (u32)s;
#pragma unroll
    for (int l = 0; l < 4; l++) {
        u16 wq[4];
#pragma unroll
        for (int k = 0; k < 4; k++) {
            float m0 = gcoef[32 + l * 8 + 2 * k], m1 = gcoef[32 + l * 8 + 2 * k + 1];
            float c0 = gcoef[l * 8 + 2 * k],      c1 = gcoef[l * 8 + 2 * k + 1];
            float d0 = a0 - m0, d1 = a1 - m1;
            float t = d0 * d0 * c0 + d1 * d1 * c1;   // t <= 0, c includes -0.5
            wq[k] = f2b(__expf(t));
        }
        uint2 o;
        o.x = (u32)wq[0] | ((u32)wq[1] << 16);
        o.y = (u32)wq[2] | ((u32)wq[3] << 16);
        agw[(size_t)l * NE + j] = o;
    }
}

// ---------------- aggregation: y[n][k*64+d] = (1/deg) sum_e gw[e][k]*x[src][d] ----------------
__global__ __launch_bounds__(256) void k_agg(const u16* __restrict__ xin,
                                             const u32* __restrict__ asrc,
                                             const uint2* __restrict__ agw,
                                             const int* __restrict__ off8,
                                             u16* __restrict__ y) {
    int wid = (blockIdx.x * 256 + threadIdx.x) >> 6;  // node, one wave each
    int lane = threadIdx.x & 63;
    int g = lane >> 4;        // edge group 0..3
    int f = lane & 15;        // feature quad: features 4f..4f+3
    if (wid >= NN) return;
    int beg = off8[wid * 8], end = off8[wid * 8 + 8];
    f32x2 acc[4][2];          // [k][pair]
#pragma unroll
    for (int k = 0; k < 4; k++) {
        acc[k][0] = (f32x2){0.f, 0.f};
        acc[k][1] = (f32x2){0.f, 0.f};
    }

    int niter = (end - beg + 3) >> 2;
#pragma unroll 2
    for (int it = 0; it < niter; it++) {
        int j = beg + it * 4 + g;
        u32 s = 0; uint2 wv = make_uint2(0, 0);     // tail: gw=0, src row 0 valid
        if (j < end) { s = asrc[j]; wv = agw[j]; }
        uint2 xr = *(const uint2*)(xin + (size_t)s * 64 + f * 4);
        f32x2 x01, x23;
        x01.x = lo16f(xr.x); x01.y = hi16f(xr.x);
        x23.x = lo16f(xr.y); x23.y = hi16f(xr.y);
        float w0 = lo16f(wv.x), w1 = hi16f(wv.x);
        float w2 = lo16f(wv.y), w3 = hi16f(wv.y);
        acc[0][0] += w0 * x01; acc[0][1] += w0 * x23;
        acc[1][0] += w1 * x01; acc[1][1] += w1 * x23;
        acc[2][0] += w2 * x01; acc[2][1] += w2 * x23;
        acc[3][0] += w3 * x01; acc[3][1] += w3 * x23;
    }

    // reduce across the 4 edge-groups (lanes differing in bits 4,5)
#pragma unroll
    for (int k = 0; k < 4; k++)
#pragma unroll
        for (int p = 0; p < 2; p++) {
            float v0 = acc[k][p].x, v1 = acc[k][p].y;
            v0 += __shfl_xor(v0, 16, 64); v0 += __shfl_xor(v0, 32, 64);
            v1 += __shfl_xor(v1, 16, 64); v1 += __shfl_xor(v1, 32, 64);
            acc[k][p].x = v0; acc[k][p].y = v1;
        }

    int deg = end - beg;
    float sc = 1.0f / (float)(deg > 1 ? deg : 1);
    u16 o0 = f2b(acc[g][0].x * sc), o1 = f2b(acc[g][0].y * sc);
    u16 o2 = f2b(acc[g][1].x * sc), o3 = f2b(acc[g][1].y * sc);
    uint2 pk;
    pk.x = (u32)o0 | ((u32)o1 << 16);
    pk.y = (u32)o2 | ((u32)o3 << 16);
    *(uint2*)(y + (size_t)wid * 256 + g * 64 + f * 4) = pk;
}

// ---------------- GEMM: xout = lrelu([y|xin](N,320) @ Wcat(320,64) + b); opt x3 = x0 + xout ----------------
#define LDA 328  // 320 + 8 u16 pad -> rows 656B, 16B aligned
__global__ __launch_bounds__(256) void k_gemm(const u16* __restrict__ y,
                                              const u16* __restrict__ xin,
                                              const u16* __restrict__ bsw,
                                              const float* __restrict__ bias,
                                              u16* __restrict__ xout,
                                              const u16* __restrict__ xadd,
                                              u16* __restrict__ x3out) {
    __shared__ u16 As[64 * LDA];
    int t = threadIdx.x;
    int rbase = blockIdx.x * 64;
#pragma unroll
    for (int c = 0; c < 10; c++) {
        int idx = t + c * 256;
        int row = idx / 40, pos = idx % 40;
        int grow = rbase + row;
        uint4 v = make_uint4(0, 0, 0, 0);
        if (grow < NN) {
            if (pos < 32) v = *(const uint4*)(y + (size_t)grow * 256 + pos * 8);
            else          v = *(const uint4*)(xin + (size_t)grow * 64 + (pos - 32) * 8);
        }
        *(uint4*)(&As[row * LDA + pos * 8]) = v;
    }
    __syncthreads();

    int wave = t >> 6, lane = t & 63, lr = lane & 15, lg = lane >> 4;
    float4v acc0 = {0.f,0.f,0.f,0.f}, acc1 = {0.f,0.f,0.f,0.f};
    float4v acc2 = {0.f,0.f,0.f,0.f}, acc3 = {0.f,0.f,0.f,0.f};
    const u16* ar = &As[(wave * 16 + lr) * LDA + lg * 8];
    const uint4* bp = (const uint4*)bsw;
    for (int kt = 0; kt < 10; kt++) {
        short8 a  = *(const short8*)(ar + kt * 32);
        short8 b0 = *(const short8*)(bp + (kt * 4 + 0) * 64 + lane);
        short8 b1 = *(const short8*)(bp + (kt * 4 + 1) * 64 + lane);
        short8 b2 = *(const short8*)(bp + (kt * 4 + 2) * 64 + lane);
        short8 b3 = *(const short8*)(bp + (kt * 4 + 3) * 64 + lane);
        acc0 = __builtin_amdgcn_mfma_f32_16x16x32_bf16(a, b0, acc0, 0, 0, 0);
        acc1 = __builtin_amdgcn_mfma_f32_16x16x32_bf16(a, b1, acc1, 0, 0, 0);
        acc2 = __builtin_amdgcn_mfma_f32_16x16x32_bf16(a, b2, acc2, 0, 0, 0);
        acc3 = __builtin_amdgcn_mfma_f32_16x16x32_bf16(a, b3, acc3, 0, 0, 0);
    }
    float4v accs[4] = {acc0, acc1, acc2, acc3};
#pragma unroll
    for (int ct = 0; ct < 4; ct++) {
        int col = ct * 16 + lr;
        float bv = bias[col];
#pragma unroll
        for (int reg = 0; reg < 4; reg++) {
            int grow = rbase + wave * 16 + lg * 4 + reg;  // C/D: row=(lane>>4)*4+reg, col=lane&15
            if (grow < NN) {
                float v = accs[ct][reg] + bv;
                v = v > 0.f ? v : 0.01f * v;
                xout[(size_t)grow * 64 + col] = f2b(v);
                if (x3out) {
                    float s2 = v + b2f(xadd[(size_t)grow * 64 + col]);
                    x3out[(size_t)grow * 64 + col] = f2b(s2);
                }
            }
        }
    }
}

// ---------------- pool stage 1: partial max over node slice, concat [x4,x1,x2,x3] ----------------
__global__ __launch_bounds__(256) void k_pool1(const u16* __restrict__ x4, const u16* __restrict__ x1,
                                               const u16* __restrict__ x2, const u16* __restrict__ x3,
                                               const int* __restrict__ startg, const int* __restrict__ endg,
                                               float* __restrict__ partial) {
    int g = blockIdx.x, sl = blockIdx.y;
    int c = threadIdx.x;
    const u16* arr = (c < 64) ? x4 : (c < 128) ? x1 : (c < 192) ? x2 : x3;
    int h = c & 63;
    int s = startg[g], e = endg[g];
    int len = e - s;
    int chunk = (len + NSL - 1) / NSL;
    int s0 = s + sl * chunk;
    int e0 = s0 + chunk; if (e0 > e) e0 = e;
    float m = -3.4e38f;
    for (int n = s0; n < e0; n++) {
        float v = b2f(arr[(size_t)n * 64 + h]);
        m = v > m ? v : m;
    }
    partial[((size_t)g * NSL + sl) * 256 + c] = m;
}

// ---------------- final MLP fused with pool stage 2 ----------------
__global__ void k_final(const float* __restrict__ partial, const float* __restrict__ w1,
                        const float* __restrict__ b1, const float* __restrict__ gamma,
                        const float* __restrict__ beta, const float* __restrict__ w2,
                        const float* __restrict__ b2v, float* __restrict__ out) {
    __shared__ float pld[256];
    __shared__ float zsh[64];
    int g = blockIdx.x, h = threadIdx.x;
    for (int c = h; c < 256; c += 64) {
        float m = -3.4e38f;
#pragma unroll
        for (int sl = 0; sl < NSL; sl++) {
            float v = partial[((size_t)g * NSL + sl) * 256 + c];
            m = v > m ? v : m;
        }
        pld[c] = m;
    }
    __syncthreads();
    float z = b1[h];
    for (int j = 0; j < 256; j++) z += pld[j] * w1[j * 64 + h];
    z = z * 0.9999950000374997f * gamma[h] + beta[h];  // /sqrt(1+1e-5)
    z = z > 0.f ? z : 0.f;
    zsh[h] = z;
    __syncthreads();
    if (h < 10) {
        float o = b2v[h];
        for (int k = 0; k < 64; k++) o += zsh[k] * w2[k * 10 + h];
        out[g * 10 + h] = o;   // fp32 output
    }
}

extern "C" void kernel_launch(void* const* d_in, const int* in_sizes, int n_in,
                              void* d_out, int out_size, void* d_ws, size_t ws_size,
                              hipStream_t stream) {
    const float* x_in    = (const float*)d_in[0];
    const int* ei_raw    = (const int*)d_in[1];
    const int* batch_raw = (const int*)d_in[2];
    const float* eattr   = (const float*)d_in[3];

    const float *g_[4], *mu_[4], *sg_[4], *rw_[4], *b_[4];
    for (int i = 0; i < 4; i++) {
        g_[i]  = (const float*)d_in[4 + 5 * i + 0];
        mu_[i] = (const float*)d_in[4 + 5 * i + 1];
        sg_[i] = (const float*)d_in[4 + 5 * i + 2];
        rw_[i] = (const float*)d_in[4 + 5 * i + 3];
        b_[i]  = (const float*)d_in[4 + 5 * i + 4];
    }
    const float* w_mlp1 = (const float*)d_in[24];
    const float* b_mlp1 = (const float*)d_in[25];
    const float* bn_g   = (const float*)d_in[26];
    const float* bn_b   = (const float*)d_in[27];
    const float* w_mlp2 = (const float*)d_in[28];
    const float* b_mlp2 = (const float*)d_in[29];
    float* out = (float*)d_out;

    // workspace carve-up (~55 MB)
    char* ws = (char*)d_ws;
    size_t o = 0;
    auto take = [&](size_t bytes) { size_t r = o; o += (bytes + 255) & ~(size_t)255; return r; };
    int*   flag     = (int*)(ws + take(4));
    float* gcoef    = (float*)(ws + take(64 * 4));
    u16*   rank     = (u16*)(ws + take((size_t)NE * 2));
    int*   cnt8     = (int*)(ws + take((size_t)NC8 * 4));
    int*   excl8    = (int*)(ws + take((size_t)NC8 * 4));
    int*   off8     = (int*)(ws + take((size_t)(NC8 + 8) * 4));
    int*   bsum     = (int*)(ws + take((size_t)NSCB * 4));
    int*   eid      = (int*)(ws + take((size_t)NE * 4));
    u32*   asrc     = (u32*)(ws + take((size_t)NE * 4));
    uint2* agw      = (uint2*)(ws + take((size_t)4 * NE * 8));
    u16*   xb       = (u16*)(ws + take((size_t)NN * 64 * 2));
    u16*   y        = (u16*)(ws + take((size_t)NN * 256 * 2));
    u16*   x0       = (u16*)(ws + take((size_t)NN * 64 * 2));
    u16*   x1       = (u16*)(ws + take((size_t)NN * 64 * 2));
    u16*   x2       = (u16*)(ws + take((size_t)NN * 64 * 2));
    u16*   x3       = (u16*)(ws + take((size_t)NN * 64 * 2));
    u16*   x4       = (u16*)(ws + take((size_t)NN * 64 * 2));
    u16*   bsw      = (u16*)(ws + take((size_t)4 * 320 * 64 * 2));
    float* partial  = (float*)(ws + take((size_t)NG * NSL * 256 * 4));
    int*   startg   = (int*)(ws + take(NG * 4));
    int*   endg     = (int*)(ws + take(NG * 4));
    (void)ws_size; (void)in_sizes; (void)n_in; (void)out_size;

    SgP SP;
    for (int i = 0; i < 4; i++) { SP.mu[i] = mu_[i]; SP.sg[i] = sg_[i]; }
    k_init<<<dim3((NC8 + 255) / 256), dim3(256), 0, stream>>>(ei_raw, flag, cnt8, startg, endg, SP, gcoef);

    WParams WP;
    for (int i = 0; i < 4; i++) { WP.g[i] = g_[i]; WP.rw[i] = rw_[i]; }
    k_cvtprep<<<dim3(16141), dim3(256), 0, stream>>>(
        ei_raw, batch_raw, flag, cnt8, rank, x_in, xb, WP, bsw, startg, endg);

    k_scanA<<<dim3(NSCB), dim3(256), 0, stream>>>(cnt8, excl8, bsum);
    k_scanBC<<<dim3(NSCB), dim3(256), 0, stream>>>(excl8, bsum, off8);
    k_scatter<<<dim3(NE / 256), dim3(256), 0, stream>>>(ei_raw, flag, off8, rank, eid);

    k_gwpack<<<dim3(NE / 256), dim3(256), 0, stream>>>(
        eid, ei_raw, (const float2*)eattr, flag, gcoef, asrc, agw);

    const int aggGrid = NN / 4;            // 4 waves (nodes) per 256-thr block
    const int gemmGrid = (NN + 63) / 64;   // 64 rows per block

    const u16* lin[4]  = {xb, x0, x1, x3};
    u16*       lout[4] = {x0, x1, x2, x4};
    for (int l = 0; l < 4; l++) {
        k_agg<<<dim3(aggGrid), dim3(256), 0, stream>>>(
            lin[l], asrc, agw + (size_t)l * NE, off8, y);
        k_gemm<<<dim3(gemmGrid), dim3(256), 0, stream>>>(
            y, lin[l], bsw + (size_t)l * 20480, b_[l], lout[l],
            (l == 2) ? x0 : (const u16*)nullptr,
            (l == 2) ? x3 : (u16*)nullptr);
    }

    k_pool1<<<dim3(NG, NSL), dim3(256), 0, stream>>>(x4, x1, x2, x3, startg, endg, partial);
    k_final<<<dim3(NG), dim3(64), 0, stream>>>(partial, w_mlp1, b_mlp1, bn_g, bn_b, w_mlp2, b_mlp2, out);
}

// Round 19
// 454.739 us; speedup vs baseline: 1.0136x; 1.0136x over previous
//
#include <hip/hip_runtime.h>
#include <hip/hip_bf16.h>

#define NN 50000
#define NE 800000
#define NG 50
#define NSL 16    // pool slices per graph
#define NSCB 196  // scan blocks (196*256 = 50176 >= NN+1 nodes)
#define NNP (NSCB * 256)        // padded node count 50176
#define NC8 (NNP * 8)           // cnt8/excl8 size 401408

typedef unsigned short u16;
typedef unsigned int u32;
typedef __attribute__((ext_vector_type(8))) short short8;
typedef __attribute__((ext_vector_type(4))) float float4v;
typedef __attribute__((ext_vector_type(2))) float f32x2;

__device__ __forceinline__ float b2f(u16 u) {
    union { u32 i; float f; } v; v.i = ((u32)u) << 16; return v.f;
}
__device__ __forceinline__ u16 f2b(float f) {
    union { float f; u32 i; } v; v.f = f;
    u32 i = v.i;
    return (u16)((i + 0x7FFFu + ((i >> 16) & 1u)) >> 16);
}
__device__ __forceinline__ float lo16f(u32 u) { union { u32 i; float f; } v; v.i = u << 16; return v.f; }
__device__ __forceinline__ float hi16f(u32 u) { union { u32 i; float f; } v; v.i = u & 0xffff0000u; return v.f; }

// ---------------- init + detect + gaussian-coef precompute ----------------
struct SgP { const float* mu[4]; const float* sg[4]; };
__global__ void k_init(const int* __restrict__ ei_raw, int* flag,
                       int* cnt8, int* startg, int* endg, SgP S, float* __restrict__ gcoef) {
    __shared__ int cs[256];
    int i = blockIdx.x * blockDim.x + threadIdx.x;
    if (i < NC8) cnt8[i] = 0;
    if (i < NG) { startg[i] = 0x7fffffff; endg[i] = 0; }
    if (blockIdx.x == 0 && threadIdx.x < 64) {
        int t = threadIdx.x;          // [l][k][d] coef then [l][k][d] mu
        int l = (t >> 3) & 3, kd = t & 7;
        if (t < 32) {
            float s = S.sg[l][kd];
            gcoef[t] = -0.5f / (1e-15f + s * s);
        } else {
            gcoef[t] = S.mu[l][kd];   // gcoef[32 + l*8 + kd]
        }
    }
    if (blockIdx.x == 1) {
        int t = threadIdx.x;
        cs[t] = (ei_raw[2 * t + 1] == 0) ? 1 : 0;
        __syncthreads();
        for (int d = 128; d > 0; d >>= 1) {
            if (t < d) cs[t] += cs[t + d];
            __syncthreads();
        }
        if (t == 0) *flag = (cs[0] >= 128) ? 1 : 0;
    }
}

// ---------------- cvt + prep mega-fusion: XCD-sharded rank-hist | x2b | wprep | bounds ----------------
struct WParams { const float* g[4]; const float* rw[4]; };
__global__ void k_cvtprep(const int* __restrict__ ei_raw, const int* __restrict__ batch_raw,
                          const int* __restrict__ flag, int* cnt8, u16* __restrict__ rank,
                          const float* __restrict__ x, u16* __restrict__ xb,
                          WParams P, u16* __restrict__ bsw,
                          int* startg, int* endg) {
    int b = blockIdx.x, t = threadIdx.x;
    if (b < 3125) {                        // rank histogram: NE = 3125*256, color = b&7 (XCD shard)
        int e = b * 256 + t;
        int w = *flag;
        int color = b & 7;
        int d = w ? ei_raw[2 * (NE + e)] : ei_raw[NE + e];
        rank[e] = (u16)atomicAdd(&cnt8[d * 8 + color], 1);
    } else if (b < 15625) {                // x2b: NN*64 = 3.2M
        int i = (b - 3125) * 256 + t;
        if (i < NN * 64) xb[i] = f2b(x[i]);
    } else if (b < 15945) {                // wprep: 4*20480 ids
        int id = (b - 15625) * 256 + t;
        if (id < 4 * 20480) {
            int l = id / 20480, r = id % 20480;
            int j = r & 7, lane = (r >> 3) & 63, ctkt = r >> 9;
            int ct = ctkt & 3, kt = ctkt >> 2;
            int k = kt * 32 + (lane >> 4) * 8 + j;
            int n = ct * 16 + (lane & 15);
            float v;
            if (k < 256) v = P.g[l][(k & 63) * 256 + (k >> 6) * 64 + n];
            else         v = P.rw[l][(k - 256) * 64 + n];
            bsw[id] = f2b(v);
        }
    } else {                               // bounds: boundary scan on raw batch
        int n = (b - 15945) * 256 + t;
        if (n >= NN) return;
        int w = *flag;
        int bb = w ? batch_raw[2 * n] : batch_raw[n];
        if (n == 0) {
            startg[bb] = 0;
        } else {
            int bp = w ? batch_raw[2 * (n - 1)] : batch_raw[n - 1];
            if (bp != bb) { startg[bb] = n; endg[bp] = n; }
        }
        if (n == NN - 1) endg[bb] = NN;
    }
}

// ---------------- scan A: one thread per node scans its 8 colors; block-scan of node sums ----------------
__global__ __launch_bounds__(256) void k_scanA(const int* __restrict__ cnt8, int* __restrict__ excl8,
                                               int* __restrict__ bsum) {
    __shared__ int s[256];
    int t = threadIdx.x, b = blockIdx.x;
    int n = b * 256 + t;                  // node (padded)
    uint4 c0 = *(const uint4*)(cnt8 + (size_t)n * 8);
    uint4 c1 = *(const uint4*)(cnt8 + (size_t)n * 8 + 4);
    int v = c0.x + c0.y + c0.z + c0.w + c1.x + c1.y + c1.z + c1.w;
    s[t] = v; __syncthreads();
    for (int d = 1; d < 256; d <<= 1) {
        int x = s[t];
        int y = (t >= d) ? s[t - d] : 0;
        __syncthreads();
        s[t] = x + y;
        __syncthreads();
    }
    int run = s[t] - v;                   // exclusive prefix within block
    uint4 e0, e1;
    e0.x = run;            e0.y = run + c0.x;
    e0.z = e0.y + c0.y;    e0.w = e0.z + c0.z;
    e1.x = e0.w + c0.w;    e1.y = e1.x + c1.x;
    e1.z = e1.y + c1.y;    e1.w = e1.z + c1.z;
    *(uint4*)(excl8 + (size_t)n * 8) = e0;
    *(uint4*)(excl8 + (size_t)n * 8 + 4) = e1;
    if (t == 255) bsum[b] = s[255];
}

// ---------------- scan B+C fused: every block re-scans bsum locally, writes off8 ----------------
__global__ __launch_bounds__(256) void k_scanBC(const int* __restrict__ excl8,
                                                const int* __restrict__ bsum,
                                                int* __restrict__ off8) {
    __shared__ int s[256];
    int t = threadIdx.x, b = blockIdx.x;
    int v = (t < NSCB) ? bsum[t] : 0;
    s[t] = v; __syncthreads();
    for (int d = 1; d < 256; d <<= 1) {
        int x = s[t];
        int y = (t >= d) ? s[t - d] : 0;
        __syncthreads();
        s[t] = x + y;
        __syncthreads();
    }
    int ebase = (b == 0) ? 0 : s[b - 1];
    int n = b * 256 + t;
    uint4 e0 = *(const uint4*)(excl8 + (size_t)n * 8);
    uint4 e1 = *(const uint4*)(excl8 + (size_t)n * 8 + 4);
    e0.x += ebase; e0.y += ebase; e0.z += ebase; e0.w += ebase;
    e1.x += ebase; e1.y += ebase; e1.z += ebase; e1.w += ebase;
    *(uint4*)(off8 + (size_t)n * 8) = e0;
    *(uint4*)(off8 + (size_t)n * 8 + 4) = e1;
}

// ---------------- scatter: atomic-free, slot = off8[dst*8+color] + rank ----------------
__global__ void k_scatter(const int* __restrict__ ei_raw, const int* __restrict__ flag,
                          const int* __restrict__ off8, const u16* __restrict__ rank,
                          int* __restrict__ eid) {
    int e = blockIdx.x * blockDim.x + threadIdx.x;
    if (e >= NE) return;
    int w = *flag;
    int color = (e >> 8) & 7;             // matches k_cvtprep's block color
    int d = w ? ei_raw[2 * (NE + e)] : ei_raw[NE + e];
    eid[off8[d * 8 + color] + (int)rank[e]] = e;
}

// ---------------- gw pack: precomputed coefs, __expf; write asrc + agw ----------------
__global__ __launch_bounds__(256) void k_gwpack(const int* __restrict__ eid,
                                                const int* __restrict__ ei_raw,
                                                const float2* __restrict__ eattr2,
                                                const int* __restrict__ flag,
                                                const float* __restrict__ gcoef,
                                                u32* __restrict__ asrc, uint2* __restrict__ agw) {
    int j = blockIdx.x * blockDim.x + threadIdx.x;
    if (j >= NE) return;
    int e = eid[j];
    int w = *flag;
    int s = w ? ei_raw[2 * e] : ei_raw[e];
    float2 at = eattr2[e];
    float a0 = at.x, a1 = at.y;
    asrc[j] = (u32)s;
#pragma unroll
    for (int l = 0; l < 4; l++) {
        u16 wq[4];
#pragma unroll
        for (int k = 0; k < 4; k++) {
            float m0 = gcoef[32 + l * 8 + 2 * k], m1 = gcoef[32 + l * 8 + 2 * k + 1];
            float c0 = gcoef[l * 8 + 2 * k],      c1 = gcoef[l * 8 + 2 * k + 1];
            float d0 = a0 - m0, d1 = a1 - m1;
            float t = d0 * d0 * c0 + d1 * d1 * c1;   // t <= 0, c includes -0.5
            wq[k] = f2b(__expf(t));
        }
        uint2 o;
        o.x = (u32)wq[0] | ((u32)wq[1] << 16);
        o.y = (u32)wq[2] | ((u32)wq[3] << 16);
        agw[(size_t)l * NE + j] = o;
    }
}

// ---------------- aggregation: batched-prefetch; 4 edge-groups x 16 lanes ----------------
// batch of 16 edges: issue all rec loads, then all x gathers, then FMAs -> 4x less exposed latency
__global__ __launch_bounds__(256) void k_agg(const u16* __restrict__ xin,
                                             const u32* __restrict__ asrc,
                                             const uint2* __restrict__ agw,
                                             const int* __restrict__ off8,
                                             u16* __restrict__ y) {
    int wid = (blockIdx.x * 256 + threadIdx.x) >> 6;  // node, one wave each
    int lane = threadIdx.x & 63;
    int g = lane >> 4;        // edge group 0..3
    int f = lane & 15;        // feature quad: features 4f..4f+3
    if (wid >= NN) return;
    int beg = off8[wid * 8], end = off8[wid * 8 + 8];
    f32x2 acc[4][2];          // [k][pair]
#pragma unroll
    for (int k = 0; k < 4; k++) {
        acc[k][0] = (f32x2){0.f, 0.f};
        acc[k][1] = (f32x2){0.f, 0.f};
    }

    int nbatch = (end - beg + 15) >> 4;   // 16 edges per batch (4 per group)
    for (int bt = 0; bt < nbatch; bt++) {
        int j0 = beg + bt * 16 + g;
        u32 s[4]; uint2 wv[4];
#pragma unroll
        for (int u = 0; u < 4; u++) {     // phase 1: all rec loads issue together
            int j = j0 + u * 4;
            s[u] = 0; wv[u] = make_uint2(0, 0);
            if (j < end) { s[u] = asrc[j]; wv[u] = agw[j]; }
        }
        uint2 xr[4];
#pragma unroll
        for (int u = 0; u < 4; u++)       // phase 2: all x gathers issue together
            xr[u] = *(const uint2*)(xin + (size_t)s[u] * 64 + f * 4);
#pragma unroll
        for (int u = 0; u < 4; u++) {     // phase 3: FMAs
            f32x2 x01, x23;
            x01.x = lo16f(xr[u].x); x01.y = hi16f(xr[u].x);
            x23.x = lo16f(xr[u].y); x23.y = hi16f(xr[u].y);
            float w0 = lo16f(wv[u].x), w1 = hi16f(wv[u].x);
            float w2 = lo16f(wv[u].y), w3 = hi16f(wv[u].y);
            acc[0][0] += w0 * x01; acc[0][1] += w0 * x23;
            acc[1][0] += w1 * x01; acc[1][1] += w1 * x23;
            acc[2][0] += w2 * x01; acc[2][1] += w2 * x23;
            acc[3][0] += w3 * x01; acc[3][1] += w3 * x23;
        }
    }

    // reduce across the 4 edge-groups (lanes differing in bits 4,5)
#pragma unroll
    for (int k = 0; k < 4; k++)
#pragma unroll
        for (int p = 0; p < 2; p++) {
            float v0 = acc[k][p].x, v1 = acc[k][p].y;
            v0 += __shfl_xor(v0, 16, 64); v0 += __shfl_xor(v0, 32, 64);
            v1 += __shfl_xor(v1, 16, 64); v1 += __shfl_xor(v1, 32, 64);
            acc[k][p].x = v0; acc[k][p].y = v1;
        }

    int deg = end - beg;
    float sc = 1.0f / (float)(deg > 1 ? deg : 1);
    u16 o0 = f2b(acc[g][0].x * sc), o1 = f2b(acc[g][0].y * sc);
    u16 o2 = f2b(acc[g][1].x * sc), o3 = f2b(acc[g][1].y * sc);
    uint2 pk;
    pk.x = (u32)o0 | ((u32)o1 << 16);
    pk.y = (u32)o2 | ((u32)o3 << 16);
    *(uint2*)(y + (size_t)wid * 256 + g * 64 + f * 4) = pk;
}

// ---------------- GEMM: xout = lrelu([y|xin](N,320) @ Wcat(320,64) + b); opt x3 = x0 + xout ----------------
#define LDA 328  // 320 + 8 u16 pad -> rows 656B, 16B aligned
__global__ __launch_bounds__(256) void k_gemm(const u16* __restrict__ y,
                                              const u16* __restrict__ xin,
                                              const u16* __restrict__ bsw,
                                              const float* __restrict__ bias,
                                              u16* __restrict__ xout,
                                              const u16* __restrict__ xadd,
                                              u16* __restrict__ x3out) {
    __shared__ u16 As[64 * LDA];
    int t = threadIdx.x;
    int rbase = blockIdx.x * 64;
#pragma unroll
    for (int c = 0; c < 10; c++) {
        int idx = t + c * 256;
        int row = idx / 40, pos = idx % 40;
        int grow = rbase + row;
        uint4 v = make_uint4(0, 0, 0, 0);
        if (grow < NN) {
            if (pos < 32) v = *(const uint4*)(y + (size_t)grow * 256 + pos * 8);
            else          v = *(const uint4*)(xin + (size_t)grow * 64 + (pos - 32) * 8);
        }
        *(uint4*)(&As[row * LDA + pos * 8]) = v;
    }
    __syncthreads();

    int wave = t >> 6, lane = t & 63, lr = lane & 15, lg = lane >> 4;
    float4v acc0 = {0.f,0.f,0.f,0.f}, acc1 = {0.f,0.f,0.f,0.f};
    float4v acc2 = {0.f,0.f,0.f,0.f}, acc3 = {0.f,0.f,0.f,0.f};
    const u16* ar = &As[(wave * 16 + lr) * LDA + lg * 8];
    const uint4* bp = (const uint4*)bsw;
    for (int kt = 0; kt < 10; kt++) {
        short8 a  = *(const short8*)(ar + kt * 32);
        short8 b0 = *(const short8*)(bp + (kt * 4 + 0) * 64 + lane);
        short8 b1 = *(const short8*)(bp + (kt * 4 + 1) * 64 + lane);
        short8 b2 = *(const short8*)(bp + (kt * 4 + 2) * 64 + lane);
        short8 b3 = *(const short8*)(bp + (kt * 4 + 3) * 64 + lane);
        acc0 = __builtin_amdgcn_mfma_f32_16x16x32_bf16(a, b0, acc0, 0, 0, 0);
        acc1 = __builtin_amdgcn_mfma_f32_16x16x32_bf16(a, b1, acc1, 0, 0, 0);
        acc2 = __builtin_amdgcn_mfma_f32_16x16x32_bf16(a, b2, acc2, 0, 0, 0);
        acc3 = __builtin_amdgcn_mfma_f32_16x16x32_bf16(a, b3, acc3, 0, 0, 0);
    }
    float4v accs[4] = {acc0, acc1, acc2, acc3};
#pragma unroll
    for (int ct = 0; ct < 4; ct++) {
        int col = ct * 16 + lr;
        float bv = bias[col];
#pragma unroll
        for (int reg = 0; reg < 4; reg++) {
            int grow = rbase + wave * 16 + lg * 4 + reg;  // C/D: row=(lane>>4)*4+reg, col=lane&15
            if (grow < NN) {
                float v = accs[ct][reg] + bv;
                v = v > 0.f ? v : 0.01f * v;
                xout[(size_t)grow * 64 + col] = f2b(v);
                if (x3out) {
                    float s2 = v + b2f(xadd[(size_t)grow * 64 + col]);
                    x3out[(size_t)grow * 64 + col] = f2b(s2);
                }
            }
        }
    }
}

// ---------------- pool stage 1: partial max over node slice, concat [x4,x1,x2,x3] ----------------
__global__ __launch_bounds__(256) void k_pool1(const u16* __restrict__ x4, const u16* __restrict__ x1,
                                               const u16* __restrict__ x2, const u16* __restrict__ x3,
                                               const int* __restrict__ startg, const int* __restrict__ endg,
                                               float* __restrict__ partial) {
    int g = blockIdx.x, sl = blockIdx.y;
    int c = threadIdx.x;
    const u16* arr = (c < 64) ? x4 : (c < 128) ? x1 : (c < 192) ? x2 : x3;
    int h = c & 63;
    int s = startg[g], e = endg[g];
    int len = e - s;
    int chunk = (len + NSL - 1) / NSL;
    int s0 = s + sl * chunk;
    int e0 = s0 + chunk; if (e0 > e) e0 = e;
    float m = -3.4e38f;
    for (int n = s0; n < e0; n++) {
        float v = b2f(arr[(size_t)n * 64 + h]);
        m = v > m ? v : m;
    }
    partial[((size_t)g * NSL + sl) * 256 + c] = m;
}

// ---------------- final MLP fused with pool stage 2 ----------------
__global__ void k_final(const float* __restrict__ partial, const float* __restrict__ w1,
                        const float* __restrict__ b1, const float* __restrict__ gamma,
                        const float* __restrict__ beta, const float* __restrict__ w2,
                        const float* __restrict__ b2v, float* __restrict__ out) {
    __shared__ float pld[256];
    __shared__ float zsh[64];
    int g = blockIdx.x, h = threadIdx.x;
    for (int c = h; c < 256; c += 64) {
        float m = -3.4e38f;
#pragma unroll
        for (int sl = 0; sl < NSL; sl++) {
            float v = partial[((size_t)g * NSL + sl) * 256 + c];
            m = v > m ? v : m;
        }
        pld[c] = m;
    }
    __syncthreads();
    float z = b1[h];
    for (int j = 0; j < 256; j++) z += pld[j] * w1[j * 64 + h];
    z = z * 0.9999950000374997f * gamma[h] + beta[h];  // /sqrt(1+1e-5)
    z = z > 0.f ? z : 0.f;
    zsh[h] = z;
    __syncthreads();
    if (h < 10) {
        float o = b2v[h];
        for (int k = 0; k < 64; k++) o += zsh[k] * w2[k * 10 + h];
        out[g * 10 + h] = o;   // fp32 output
    }
}

extern "C" void kernel_launch(void* const* d_in, const int* in_sizes, int n_in,
                              void* d_out, int out_size, void* d_ws, size_t ws_size,
                              hipStream_t stream) {
    const float* x_in    = (const float*)d_in[0];
    const int* ei_raw    = (const int*)d_in[1];
    const int* batch_raw = (const int*)d_in[2];
    const float* eattr   = (const float*)d_in[3];

    const float *g_[4], *mu_[4], *sg_[4], *rw_[4], *b_[4];
    for (int i = 0; i < 4; i++) {
        g_[i]  = (const float*)d_in[4 + 5 * i + 0];
        mu_[i] = (const float*)d_in[4 + 5 * i + 1];
        sg_[i] = (const float*)d_in[4 + 5 * i + 2];
        rw_[i] = (const float*)d_in[4 + 5 * i + 3];
        b_[i]  = (const float*)d_in[4 + 5 * i + 4];
    }
    const float* w_mlp1 = (const float*)d_in[24];
    const float* b_mlp1 = (const float*)d_in[25];
    const float* bn_g   = (const float*)d_in[26];
    const float* bn_b   = (const float*)d_in[27];
    const float* w_mlp2 = (const float*)d_in[28];
    const float* b_mlp2 = (const float*)d_in[29];
    float* out = (float*)d_out;

    // workspace carve-up (~55 MB)
    char* ws = (char*)d_ws;
    size_t o = 0;
    auto take = [&](size_t bytes) { size_t r = o; o += (bytes + 255) & ~(size_t)255; return r; };
    int*   flag     = (int*)(ws + take(4));
    float* gcoef    = (float*)(ws + take(64 * 4));
    u16*   rank     = (u16*)(ws + take((size_t)NE * 2));
    int*   cnt8     = (int*)(ws + take((size_t)NC8 * 4));
    int*   excl8    = (int*)(ws + take((size_t)NC8 * 4));
    int*   off8     = (int*)(ws + take((size_t)(NC8 + 8) * 4));
    int*   bsum     = (int*)(ws + take((size_t)NSCB * 4));
    int*   eid      = (int*)(ws + take((size_t)NE * 4));
    u32*   asrc     = (u32*)(ws + take((size_t)NE * 4));
    uint2* agw      = (uint2*)(ws + take((size_t)4 * NE * 8));
    u16*   xb       = (u16*)(ws + take((size_t)NN * 64 * 2));
    u16*   y        = (u16*)(ws + take((size_t)NN * 256 * 2));
    u16*   x0       = (u16*)(ws + take((size_t)NN * 64 * 2));
    u16*   x1       = (u16*)(ws + take((size_t)NN * 64 * 2));
    u16*   x2       = (u16*)(ws + take((size_t)NN * 64 * 2));
    u16*   x3       = (u16*)(ws + take((size_t)NN * 64 * 2));
    u16*   x4       = (u16*)(ws + take((size_t)NN * 64 * 2));
    u16*   bsw      = (u16*)(ws + take((size_t)4 * 320 * 64 * 2));
    float* partial  = (float*)(ws + take((size_t)NG * NSL * 256 * 4));
    int*   startg   = (int*)(ws + take(NG * 4));
    int*   endg     = (int*)(ws + take(NG * 4));
    (void)ws_size; (void)in_sizes; (void)n_in; (void)out_size;

    SgP SP;
    for (int i = 0; i < 4; i++) { SP.mu[i] = mu_[i]; SP.sg[i] = sg_[i]; }
    k_init<<<dim3((NC8 + 255) / 256), dim3(256), 0, stream>>>(ei_raw, flag, cnt8, startg, endg, SP, gcoef);

    WParams WP;
    for (int i = 0; i < 4; i++) { WP.g[i] = g_[i]; WP.rw[i] = rw_[i]; }
    k_cvtprep<<<dim3(16141), dim3(256), 0, stream>>>(
        ei_raw, batch_raw, flag, cnt8, rank, x_in, xb, WP, bsw, startg, endg);

    k_scanA<<<dim3(NSCB), dim3(256), 0, stream>>>(cnt8, excl8, bsum);
    k_scanBC<<<dim3(NSCB), dim3(256), 0, stream>>>(excl8, bsum, off8);
    k_scatter<<<dim3(NE / 256), dim3(256), 0, stream>>>(ei_raw, flag, off8, rank, eid);

    k_gwpack<<<dim3(NE / 256), dim3(256), 0, stream>>>(
        eid, ei_raw, (const float2*)eattr, flag, gcoef, asrc, agw);

    const int aggGrid = NN / 4;            // 4 waves (nodes) per 256-thr block
    const int gemmGrid = (NN + 63) / 64;   // 64 rows per block

    const u16* lin[4]  = {xb, x0, x1, x3};
    u16*       lout[4] = {x0, x1, x2, x4};
    for (int l = 0; l < 4; l++) {
        k_agg<<<dim3(aggGrid), dim3(256), 0, stream>>>(
            lin[l], asrc, agw + (size_t)l * NE, off8, y);
        k_gemm<<<dim3(gemmGrid), dim3(256), 0, stream>>>(
            y, lin[l], bsw + (size_t)l * 20480, b_[l], lout[l],
            (l == 2) ? x0 : (const u16*)nullptr,
            (l == 2) ? x3 : (u16*)nullptr);
    }

    k_pool1<<<dim3(NG, NSL), dim3(256), 0, stream>>>(x4, x1, x2, x3, startg, endg, partial);
    k_final<<<dim3(NG), dim3(64), 0, stream>>>(partial, w_mlp1, b_mlp1, bn_g, bn_b, w_mlp2, b_mlp2, out);
}

// Round 20
// 452.756 us; speedup vs baseline: 1.0180x; 1.0044x over previous
//
#include <hip/hip_runtime.h>
#include <hip/hip_bf16.h>

#define NN 50000
#define NE 800000
#define NG 50
#define NSL 16    // pool slices per graph
#define NSCB 196  // scan blocks (196*256 = 50176 >= NN+1 nodes)
#define NNP (NSCB * 256)        // padded node count 50176
#define NC8 (NNP * 8)           // cnt8/excl8 size 401408

typedef unsigned short u16;
typedef unsigned int u32;
typedef __attribute__((ext_vector_type(8))) short short8;
typedef __attribute__((ext_vector_type(4))) float float4v;
typedef __attribute__((ext_vector_type(2))) float f32x2;

__device__ __forceinline__ float b2f(u16 u) {
    union { u32 i; float f; } v; v.i = ((u32)u) << 16; return v.f;
}
__device__ __forceinline__ u16 f2b(float f) {
    union { float f; u32 i; } v; v.f = f;
    u32 i = v.i;
    return (u16)((i + 0x7FFFu + ((i >> 16) & 1u)) >> 16);
}
__device__ __forceinline__ float lo16f(u32 u) { union { u32 i; float f; } v; v.i = u << 16; return v.f; }
__device__ __forceinline__ float hi16f(u32 u) { union { u32 i; float f; } v; v.i = u & 0xffff0000u; return v.f; }

// ---------------- init + detect + gaussian-coef precompute ----------------
struct SgP { const float* mu[4]; const float* sg[4]; };
__global__ void k_init(const int* __restrict__ ei_raw, int* flag,
                       int* cnt8, int* startg, int* endg, SgP S, float* __restrict__ gcoef) {
    __shared__ int cs[256];
    int i = blockIdx.x * blockDim.x + threadIdx.x;
    if (i < NC8) cnt8[i] = 0;
    if (i < NG) { startg[i] = 0x7fffffff; endg[i] = 0; }
    if (blockIdx.x == 0 && threadIdx.x < 64) {
        int t = threadIdx.x;          // [l][k][d] coef then [l][k][d] mu
        int l = (t >> 3) & 3, kd = t & 7;
        if (t < 32) {
            float s = S.sg[l][kd];
            gcoef[t] = -0.5f / (1e-15f + s * s);
        } else {
            gcoef[t] = S.mu[l][kd];   // gcoef[32 + l*8 + kd]
        }
    }
    if (blockIdx.x == 1) {
        int t = threadIdx.x;
        cs[t] = (ei_raw[2 * t + 1] == 0) ? 1 : 0;
        __syncthreads();
        for (int d = 128; d > 0; d >>= 1) {
            if (t < d) cs[t] += cs[t + d];
            __syncthreads();
        }
        if (t == 0) *flag = (cs[0] >= 128) ? 1 : 0;
    }
}

// ---------------- cvt + prep mega-fusion: src-range-sharded rank-hist | x2b | wprep | bounds ----------------
struct WParams { const float* g[4]; const float* rw[4]; };
__global__ void k_cvtprep(const int* __restrict__ ei_raw, const int* __restrict__ batch_raw,
                          const int* __restrict__ flag, int* cnt8, u16* __restrict__ rank,
                          const float* __restrict__ x, u16* __restrict__ xb,
                          WParams P, u16* __restrict__ bsw,
                          int* startg, int* endg) {
    int b = blockIdx.x, t = threadIdx.x;
    if (b < 3125) {                        // rank histogram: color = src/6250 (src-range shard)
        int e = b * 256 + t;
        int w = *flag;
        int s = w ? ei_raw[2 * e] : ei_raw[e];
        int d = w ? ei_raw[2 * (NE + e)] : ei_raw[NE + e];
        int color = s / 6250;              // 0..7
        rank[e] = (u16)atomicAdd(&cnt8[d * 8 + color], 1);
    } else if (b < 15625) {                // x2b: NN*64 = 3.2M
        int i = (b - 3125) * 256 + t;
        if (i < NN * 64) xb[i] = f2b(x[i]);
    } else if (b < 15945) {                // wprep: 4*20480 ids
        int id = (b - 15625) * 256 + t;
        if (id < 4 * 20480) {
            int l = id / 20480, r = id % 20480;
            int j = r & 7, lane = (r >> 3) & 63, ctkt = r >> 9;
            int ct = ctkt & 3, kt = ctkt >> 2;
            int k = kt * 32 + (lane >> 4) * 8 + j;
            int n = ct * 16 + (lane & 15);
            float v;
            if (k < 256) v = P.g[l][(k & 63) * 256 + (k >> 6) * 64 + n];
            else         v = P.rw[l][(k - 256) * 64 + n];
            bsw[id] = f2b(v);
        }
    } else {                               // bounds: boundary scan on raw batch
        int n = (b - 15945) * 256 + t;
        if (n >= NN) return;
        int w = *flag;
        int bb = w ? batch_raw[2 * n] : batch_raw[n];
        if (n == 0) {
            startg[bb] = 0;
        } else {
            int bp = w ? batch_raw[2 * (n - 1)] : batch_raw[n - 1];
            if (bp != bb) { startg[bb] = n; endg[bp] = n; }
        }
        if (n == NN - 1) endg[bb] = NN;
    }
}

// ---------------- scan A: one thread per node scans its 8 colors; block-scan of node sums ----------------
__global__ __launch_bounds__(256) void k_scanA(const int* __restrict__ cnt8, int* __restrict__ excl8,
                                               int* __restrict__ bsum) {
    __shared__ int s[256];
    int t = threadIdx.x, b = blockIdx.x;
    int n = b * 256 + t;                  // node (padded)
    uint4 c0 = *(const uint4*)(cnt8 + (size_t)n * 8);
    uint4 c1 = *(const uint4*)(cnt8 + (size_t)n * 8 + 4);
    int v = c0.x + c0.y + c0.z + c0.w + c1.x + c1.y + c1.z + c1.w;
    s[t] = v; __syncthreads();
    for (int d = 1; d < 256; d <<= 1) {
        int x = s[t];
        int y = (t >= d) ? s[t - d] : 0;
        __syncthreads();
        s[t] = x + y;
        __syncthreads();
    }
    int run = s[t] - v;                   // exclusive prefix within block
    uint4 e0, e1;
    e0.x = run;            e0.y = run + c0.x;
    e0.z = e0.y + c0.y;    e0.w = e0.z + c0.z;
    e1.x = e0.w + c0.w;    e1.y = e1.x + c1.x;
    e1.z = e1.y + c1.y;    e1.w = e1.z + c1.z;
    *(uint4*)(excl8 + (size_t)n * 8) = e0;
    *(uint4*)(excl8 + (size_t)n * 8 + 4) = e1;
    if (t == 255) bsum[b] = s[255];
}

// ---------------- scan B+C fused: every block re-scans bsum locally, writes off8 ----------------
__global__ __launch_bounds__(256) void k_scanBC(const int* __restrict__ excl8,
                                                const int* __restrict__ bsum,
                                                int* __restrict__ off8) {
    __shared__ int s[256];
    int t = threadIdx.x, b = blockIdx.x;
    int v = (t < NSCB) ? bsum[t] : 0;
    s[t] = v; __syncthreads();
    for (int d = 1; d < 256; d <<= 1) {
        int x = s[t];
        int y = (t >= d) ? s[t - d] : 0;
        __syncthreads();
        s[t] = x + y;
        __syncthreads();
    }
    int ebase = (b == 0) ? 0 : s[b - 1];
    int n = b * 256 + t;
    uint4 e0 = *(const uint4*)(excl8 + (size_t)n * 8);
    uint4 e1 = *(const uint4*)(excl8 + (size_t)n * 8 + 4);
    e0.x += ebase; e0.y += ebase; e0.z += ebase; e0.w += ebase;
    e1.x += ebase; e1.y += ebase; e1.z += ebase; e1.w += ebase;
    *(uint4*)(off8 + (size_t)n * 8) = e0;
    *(uint4*)(off8 + (size_t)n * 8 + 4) = e1;
}

// ---------------- scatter: atomic-free, slot = off8[dst*8+color] + rank ----------------
__global__ void k_scatter(const int* __restrict__ ei_raw, const int* __restrict__ flag,
                          const int* __restrict__ off8, const u16* __restrict__ rank,
                          int* __restrict__ eid) {
    int e = blockIdx.x * blockDim.x + threadIdx.x;
    if (e >= NE) return;
    int w = *flag;
    int s = w ? ei_raw[2 * e] : ei_raw[e];
    int d = w ? ei_raw[2 * (NE + e)] : ei_raw[NE + e];
    int color = s / 6250;                 // matches k_cvtprep's color
    eid[off8[d * 8 + color] + (int)rank[e]] = e;
}

// ---------------- gw pack: precomputed coefs, __expf; write asrc + agw ----------------
__global__ __launch_bounds__(256) void k_gwpack(const int* __restrict__ eid,
                                                const int* __restrict__ ei_raw,
                                                const float2* __restrict__ eattr2,
                                                const int* __restrict__ flag,
                                                const float* __restrict__ gcoef,
                                                u32* __restrict__ asrc, uint2* __restrict__ agw) {
    int j = blockIdx.x * blockDim.x + threadIdx.x;
    if (j >= NE) return;
    int e = eid[j];
    int w = *flag;
    int s = w ? ei_raw[2 * e] : ei_raw[e];
    float2 at = eattr2[e];
    float a0 = at.x, a1 = at.y;
    asrc[j] = (u32)s;
#pragma unroll
    for (int l = 0; l < 4; l++) {
        u16 wq[4];
#pragma unroll
        for (int k = 0; k < 4; k++) {
            float m0 = gcoef[32 + l * 8 + 2 * k], m1 = gcoef[32 + l * 8 + 2 * k + 1];
            float c0 = gcoef[l * 8 + 2 * k],      c1 = gcoef[l * 8 + 2 * k + 1];
            float d0 = a0 - m0, d1 = a1 - m1;
            float t = d0 * d0 * c0 + d1 * d1 * c1;   // t <= 0, c includes -0.5
            wq[k] = f2b(__expf(t));
        }
        uint2 o;
        o.x = (u32)wq[0] | ((u32)wq[1] << 16);
        o.y = (u32)wq[2] | ((u32)wq[3] << 16);
        agw[(size_t)l * NE + j] = o;
    }
}

// ---------------- aggregation: batched-prefetch; 4 edge-groups x 16 lanes ----------------
__global__ __launch_bounds__(256) void k_agg(const u16* __restrict__ xin,
                                             const u32* __restrict__ asrc,
                                             const uint2* __restrict__ agw,
                                             const int* __restrict__ off8,
                                             u16* __restrict__ y) {
    int wid = (blockIdx.x * 256 + threadIdx.x) >> 6;  // node, one wave each
    int lane = threadIdx.x & 63;
    int g = lane >> 4;        // edge group 0..3
    int f = lane & 15;        // feature quad: features 4f..4f+3
    if (wid >= NN) return;
    int beg = off8[wid * 8], end = off8[wid * 8 + 8];
    f32x2 acc[4][2];          // [k][pair]
#pragma unroll
    for (int k = 0; k < 4; k++) {
        acc[k][0] = (f32x2){0.f, 0.f};
        acc[k][1] = (f32x2){0.f, 0.f};
    }

    int nbatch = (end - beg + 15) >> 4;   // 16 edges per batch (4 per group)
    for (int bt = 0; bt < nbatch; bt++) {
        int j0 = beg + bt * 16 + g;
        u32 s[4]; uint2 wv[4];
#pragma unroll
        for (int u = 0; u < 4; u++) {     // phase 1: all rec loads issue together
            int j = j0 + u * 4;
            s[u] = 0; wv[u] = make_uint2(0, 0);
            if (j < end) { s[u] = asrc[j]; wv[u] = agw[j]; }
        }
        uint2 xr[4];
#pragma unroll
        for (int u = 0; u < 4; u++)       // phase 2: all x gathers issue together
            xr[u] = *(const uint2*)(xin + (size_t)s[u] * 64 + f * 4);
#pragma unroll
        for (int u = 0; u < 4; u++) {     // phase 3: FMAs
            f32x2 x01, x23;
            x01.x = lo16f(xr[u].x); x01.y = hi16f(xr[u].x);
            x23.x = lo16f(xr[u].y); x23.y = hi16f(xr[u].y);
            float w0 = lo16f(wv[u].x), w1 = hi16f(wv[u].x);
            float w2 = lo16f(wv[u].y), w3 = hi16f(wv[u].y);
            acc[0][0] += w0 * x01; acc[0][1] += w0 * x23;
            acc[1][0] += w1 * x01; acc[1][1] += w1 * x23;
            acc[2][0] += w2 * x01; acc[2][1] += w2 * x23;
            acc[3][0] += w3 * x01; acc[3][1] += w3 * x23;
        }
    }

    // reduce across the 4 edge-groups (lanes differing in bits 4,5)
#pragma unroll
    for (int k = 0; k < 4; k++)
#pragma unroll
        for (int p = 0; p < 2; p++) {
            float v0 = acc[k][p].x, v1 = acc[k][p].y;
            v0 += __shfl_xor(v0, 16, 64); v0 += __shfl_xor(v0, 32, 64);
            v1 += __shfl_xor(v1, 16, 64); v1 += __shfl_xor(v1, 32, 64);
            acc[k][p].x = v0; acc[k][p].y = v1;
        }

    int deg = end - beg;
    float sc = 1.0f / (float)(deg > 1 ? deg : 1);
    u16 o0 = f2b(acc[g][0].x * sc), o1 = f2b(acc[g][0].y * sc);
    u16 o2 = f2b(acc[g][1].x * sc), o3 = f2b(acc[g][1].y * sc);
    uint2 pk;
    pk.x = (u32)o0 | ((u32)o1 << 16);
    pk.y = (u32)o2 | ((u32)o3 << 16);
    *(uint2*)(y + (size_t)wid * 256 + g * 64 + f * 4) = pk;
}

// ---------------- GEMM: xout = lrelu([y|xin](N,320) @ Wcat(320,64) + b); opt x3 = x0 + xout ----------------
#define LDA 328  // 320 + 8 u16 pad -> rows 656B, 16B aligned
__global__ __launch_bounds__(256) void k_gemm(const u16* __restrict__ y,
                                              const u16* __restrict__ xin,
                                              const u16* __restrict__ bsw,
                                              const float* __restrict__ bias,
                                              u16* __restrict__ xout,
                                              const u16* __restrict__ xadd,
                                              u16* __restrict__ x3out) {
    __shared__ u16 As[64 * LDA];
    int t = threadIdx.x;
    int rbase = blockIdx.x * 64;
#pragma unroll
    for (int c = 0; c < 10; c++) {
        int idx = t + c * 256;
        int row = idx / 40, pos = idx % 40;
        int grow = rbase + row;
        uint4 v = make_uint4(0, 0, 0, 0);
        if (grow < NN) {
            if (pos < 32) v = *(const uint4*)(y + (size_t)grow * 256 + pos * 8);
            else          v = *(const uint4*)(xin + (size_t)grow * 64 + (pos - 32) * 8);
        }
        *(uint4*)(&As[row * LDA + pos * 8]) = v;
    }
    __syncthreads();

    int wave = t >> 6, lane = t & 63, lr = lane & 15, lg = lane >> 4;
    float4v acc0 = {0.f,0.f,0.f,0.f}, acc1 = {0.f,0.f,0.f,0.f};
    float4v acc2 = {0.f,0.f,0.f,0.f}, acc3 = {0.f,0.f,0.f,0.f};
    const u16* ar = &As[(wave * 16 + lr) * LDA + lg * 8];
    const uint4* bp = (const uint4*)bsw;
    for (int kt = 0; kt < 10; kt++) {
        short8 a  = *(const short8*)(ar + kt * 32);
        short8 b0 = *(const short8*)(bp + (kt * 4 + 0) * 64 + lane);
        short8 b1 = *(const short8*)(bp + (kt * 4 + 1) * 64 + lane);
        short8 b2 = *(const short8*)(bp + (kt * 4 + 2) * 64 + lane);
        short8 b3 = *(const short8*)(bp + (kt * 4 + 3) * 64 + lane);
        acc0 = __builtin_amdgcn_mfma_f32_16x16x32_bf16(a, b0, acc0, 0, 0, 0);
        acc1 = __builtin_amdgcn_mfma_f32_16x16x32_bf16(a, b1, acc1, 0, 0, 0);
        acc2 = __builtin_amdgcn_mfma_f32_16x16x32_bf16(a, b2, acc2, 0, 0, 0);
        acc3 = __builtin_amdgcn_mfma_f32_16x16x32_bf16(a, b3, acc3, 0, 0, 0);
    }
    float4v accs[4] = {acc0, acc1, acc2, acc3};
#pragma unroll
    for (int ct = 0; ct < 4; ct++) {
        int col = ct * 16 + lr;
        float bv = bias[col];
#pragma unroll
        for (int reg = 0; reg < 4; reg++) {
            int grow = rbase + wave * 16 + lg * 4 + reg;  // C/D: row=(lane>>4)*4+reg, col=lane&15
            if (grow < NN) {
                float v = accs[ct][reg] + bv;
                v = v > 0.f ? v : 0.01f * v;
                xout[(size_t)grow * 64 + col] = f2b(v);
                if (x3out) {
                    float s2 = v + b2f(xadd[(size_t)grow * 64 + col]);
                    x3out[(size_t)grow * 64 + col] = f2b(s2);
                }
            }
        }
    }
}

// ---------------- pool stage 1: partial max over node slice, concat [x4,x1,x2,x3] ----------------
__global__ __launch_bounds__(256) void k_pool1(const u16* __restrict__ x4, const u16* __restrict__ x1,
                                               const u16* __restrict__ x2, const u16* __restrict__ x3,
                                               const int* __restrict__ startg, const int* __restrict__ endg,
                                               float* __restrict__ partial) {
    int g = blockIdx.x, sl = blockIdx.y;
    int c = threadIdx.x;
    const u16* arr = (c < 64) ? x4 : (c < 128) ? x1 : (c < 192) ? x2 : x3;
    int h = c & 63;
    int s = startg[g], e = endg[g];
    int len = e - s;
    int chunk = (len + NSL - 1) / NSL;
    int s0 = s + sl * chunk;
    int e0 = s0 + chunk; if (e0 > e) e0 = e;
    float m = -3.4e38f;
    for (int n = s0; n < e0; n++) {
        float v = b2f(arr[(size_t)n * 64 + h]);
        m = v > m ? v : m;
    }
    partial[((size_t)g * NSL + sl) * 256 + c] = m;
}

// ---------------- final MLP fused with pool stage 2 ----------------
__global__ void k_final(const float* __restrict__ partial, const float* __restrict__ w1,
                        const float* __restrict__ b1, const float* __restrict__ gamma,
                        const float* __restrict__ beta, const float* __restrict__ w2,
                        const float* __restrict__ b2v, float* __restrict__ out) {
    __shared__ float pld[256];
    __shared__ float zsh[64];
    int g = blockIdx.x, h = threadIdx.x;
    for (int c = h; c < 256; c += 64) {
        float m = -3.4e38f;
#pragma unroll
        for (int sl = 0; sl < NSL; sl++) {
            float v = partial[((size_t)g * NSL + sl) * 256 + c];
            m = v > m ? v : m;
        }
        pld[c] = m;
    }
    __syncthreads();
    float z = b1[h];
    for (int j = 0; j < 256; j++) z += pld[j] * w1[j * 64 + h];
    z = z * 0.9999950000374997f * gamma[h] + beta[h];  // /sqrt(1+1e-5)
    z = z > 0.f ? z : 0.f;
    zsh[h] = z;
    __syncthreads();
    if (h < 10) {
        float o = b2v[h];
        for (int k = 0; k < 64; k++) o += zsh[k] * w2[k * 10 + h];
        out[g * 10 + h] = o;   // fp32 output
    }
}

extern "C" void kernel_launch(void* const* d_in, const int* in_sizes, int n_in,
                              void* d_out, int out_size, void* d_ws, size_t ws_size,
                              hipStream_t stream) {
    const float* x_in    = (const float*)d_in[0];
    const int* ei_raw    = (const int*)d_in[1];
    const int* batch_raw = (const int*)d_in[2];
    const float* eattr   = (const float*)d_in[3];

    const float *g_[4], *mu_[4], *sg_[4], *rw_[4], *b_[4];
    for (int i = 0; i < 4; i++) {
        g_[i]  = (const float*)d_in[4 + 5 * i + 0];
        mu_[i] = (const float*)d_in[4 + 5 * i + 1];
        sg_[i] = (const float*)d_in[4 + 5 * i + 2];
        rw_[i] = (const float*)d_in[4 + 5 * i + 3];
        b_[i]  = (const float*)d_in[4 + 5 * i + 4];
    }
    const float* w_mlp1 = (const float*)d_in[24];
    const float* b_mlp1 = (const float*)d_in[25];
    const float* bn_g   = (const float*)d_in[26];
    const float* bn_b   = (const float*)d_in[27];
    const float* w_mlp2 = (const float*)d_in[28];
    const float* b_mlp2 = (const float*)d_in[29];
    float* out = (float*)d_out;

    // workspace carve-up (~55 MB)
    char* ws = (char*)d_ws;
    size_t o = 0;
    auto take = [&](size_t bytes) { size_t r = o; o += (bytes + 255) & ~(size_t)255; return r; };
    int*   flag     = (int*)(ws + take(4));
    float* gcoef    = (float*)(ws + take(64 * 4));
    u16*   rank     = (u16*)(ws + take((size_t)NE * 2));
    int*   cnt8     = (int*)(ws + take((size_t)NC8 * 4));
    int*   excl8    = (int*)(ws + take((size_t)NC8 * 4));
    int*   off8     = (int*)(ws + take((size_t)(NC8 + 8) * 4));
    int*   bsum     = (int*)(ws + take((size_t)NSCB * 4));
    int*   eid      = (int*)(ws + take((size_t)NE * 4));
    u32*   asrc     = (u32*)(ws + take((size_t)NE * 4));
    uint2* agw      = (uint2*)(ws + take((size_t)4 * NE * 8));
    u16*   xb       = (u16*)(ws + take((size_t)NN * 64 * 2));
    u16*   y        = (u16*)(ws + take((size_t)NN * 256 * 2));
    u16*   x0       = (u16*)(ws + take((size_t)NN * 64 * 2));
    u16*   x1       = (u16*)(ws + take((size_t)NN * 64 * 2));
    u16*   x2       = (u16*)(ws + take((size_t)NN * 64 * 2));
    u16*   x3       = (u16*)(ws + take((size_t)NN * 64 * 2));
    u16*   x4       = (u16*)(ws + take((size_t)NN * 64 * 2));
    u16*   bsw      = (u16*)(ws + take((size_t)4 * 320 * 64 * 2));
    float* partial  = (float*)(ws + take((size_t)NG * NSL * 256 * 4));
    int*   startg   = (int*)(ws + take(NG * 4));
    int*   endg     = (int*)(ws + take(NG * 4));
    (void)ws_size; (void)in_sizes; (void)n_in; (void)out_size;

    SgP SP;
    for (int i = 0; i < 4; i++) { SP.mu[i] = mu_[i]; SP.sg[i] = sg_[i]; }
    k_init<<<dim3((NC8 + 255) / 256), dim3(256), 0, stream>>>(ei_raw, flag, cnt8, startg, endg, SP, gcoef);

    WParams WP;
    for (int i = 0; i < 4; i++) { WP.g[i] = g_[i]; WP.rw[i] = rw_[i]; }
    k_cvtprep<<<dim3(16141), dim3(256), 0, stream>>>(
        ei_raw, batch_raw, flag, cnt8, rank, x_in, xb, WP, bsw, startg, endg);

    k_scanA<<<dim3(NSCB), dim3(256), 0, stream>>>(cnt8, excl8, bsum);
    k_scanBC<<<dim3(NSCB), dim3(256), 0, stream>>>(excl8, bsum, off8);
    k_scatter<<<dim3(NE / 256), dim3(256), 0, stream>>>(ei_raw, flag, off8, rank, eid);

    k_gwpack<<<dim3(NE / 256), dim3(256), 0, stream>>>(
        eid, ei_raw, (const float2*)eattr, flag, gcoef, asrc, agw);

    const int aggGrid = NN / 4;            // 4 waves (nodes) per 256-thr block
    const int gemmGrid = (NN + 63) / 64;   // 64 rows per block

    const u16* lin[4]  = {xb, x0, x1, x3};
    u16*       lout[4] = {x0, x1, x2, x4};
    for (int l = 0; l < 4; l++) {
        k_agg<<<dim3(aggGrid), dim3(256), 0, stream>>>(
            lin[l], asrc, agw + (size_t)l * NE, off8, y);
        k_gemm<<<dim3(gemmGrid), dim3(256), 0, stream>>>(
            y, lin[l], bsw + (size_t)l * 20480, b_[l], lout[l],
            (l == 2) ? x0 : (const u16*)nullptr,
            (l == 2) ? x3 : (u16*)nullptr);
    }

    k_pool1<<<dim3(NG, NSL), dim3(256), 0, stream>>>(x4, x1, x2, x3, startg, endg, partial);
    k_final<<<dim3(NG), dim3(64), 0, stream>>>(partial, w_mlp1, b_mlp1, bn_g, bn_b, w_mlp2, b_mlp2, out);
}